// Round 5
// baseline (285.650 us; speedup 1.0000x reference)
//
#include <hip/hip_runtime.h>
#include <hip/hip_bf16.h>
#include <math.h>

constexpr int F = 128;        // in features
constexpr int H = 64;         // out features
constexpr int NB = 32;        // nodes per gemm block
constexpr int XS_STRIDE = F + 4;

#define MASK40 ((1ull << 40) - 1)
#define Q24 16777216.0f

__device__ __forceinline__ float blo(unsigned u) { return __uint_as_float(u << 16); }
__device__ __forceinline__ float bhi(unsigned u) { return __uint_as_float(u & 0xffff0000u); }

// ------------- init: pk = 0, gacc = 0, done = 0 -----------------------------
__global__ __launch_bounds__(256) void k_init(unsigned long long* __restrict__ pk,
                                              float* __restrict__ gacc,
                                              unsigned int* __restrict__ done, int N) {
  int i = blockIdx.x * 256 + threadIdx.x;
  if (i < N) pk[i] = 0ull;
  if (i == 0) { gacc[0] = 0.0f; done[0] = 0u; }
}

// ------------- fused: gemm blocks [0,G) | count blocks [G, G+C) -------------
__global__ __launch_bounds__(256) void k_mix(const float* __restrict__ x,
                                             const float* __restrict__ W,
                                             unsigned short* __restrict__ hb, int N,
                                             const int* __restrict__ dst,
                                             const float* __restrict__ w,
                                             unsigned long long* __restrict__ pk,
                                             int* __restrict__ rank, int E, int G) {
  __shared__ float Ws[F * H];
  __shared__ float xs[NB * XS_STRIDE];
  if ((int)blockIdx.x >= G) {
    // ---- count: one packed atomic per edge; cnt hi, Q24 deg lo; rank = old
    int e = ((int)blockIdx.x - G) * 256 + threadIdx.x;
    if (e < E) {
      int d = dst[e];
      unsigned long long enc =
          (1ull << 40) | (unsigned long long)__float2uint_rn(w[e] * Q24);
      unsigned long long old = atomicAdd(&pk[d], enc);
      rank[e] = (int)(old >> 40);
    }
    return;
  }
  // ---- gemm: h = x @ W, bf16 output
  const int t = threadIdx.x;
  {
    const float4* W4 = (const float4*)W;
    float4* Ws4 = (float4*)Ws;
#pragma unroll
    for (int i = 0; i < (F * H / 4) / 256; ++i) Ws4[t + i * 256] = W4[t + i * 256];
  }
  const int node0 = blockIdx.x * NB;
  {
    const float4* x4 = (const float4*)(x + (size_t)node0 * F);
    int lim = (N - node0 < NB ? N - node0 : NB) * (F / 4);
    for (int i = t; i < NB * (F / 4); i += 256) {
      int nl = i / (F / 4), kk = i % (F / 4);
      float4 v = (i < lim) ? x4[i] : make_float4(0.f, 0.f, 0.f, 0.f);
      *(float4*)&xs[nl * XS_STRIDE + kk * 4] = v;
    }
  }
  __syncthreads();
  const int f0 = (t & 15) * 4;
  const int nl0 = (t >> 4) * 2;
  float acc[2][4] = {};
  for (int k = 0; k < F; k += 4) {
    float xr[2][4];
    float wr[4][4];
    *(float4*)&xr[0][0] = *(const float4*)&xs[(nl0 + 0) * XS_STRIDE + k];
    *(float4*)&xr[1][0] = *(const float4*)&xs[(nl0 + 1) * XS_STRIDE + k];
#pragma unroll
    for (int i = 0; i < 4; ++i)
      *(float4*)&wr[i][0] = *(const float4*)&Ws[(k + i) * H + f0];
#pragma unroll
    for (int i = 0; i < 4; ++i)
#pragma unroll
      for (int n = 0; n < 2; ++n)
#pragma unroll
        for (int j = 0; j < 4; ++j)
          acc[n][j] += xr[n][i] * wr[i][j];
  }
#pragma unroll
  for (int n = 0; n < 2; ++n) {
    int node = node0 + nl0 + n;
    if (node < N) {
      ushort4 o;
      o.x = __bfloat16_as_ushort(__float2bfloat16(acc[n][0]));
      o.y = __bfloat16_as_ushort(__float2bfloat16(acc[n][1]));
      o.z = __bfloat16_as_ushort(__float2bfloat16(acc[n][2]));
      o.w = __bfloat16_as_ushort(__float2bfloat16(acc[n][3]));
      *(ushort4*)&hb[(size_t)node * H + f0] = o;
    }
  }
}

// ---- scan phase 1: unpack cnt/dinv, per-block exclusive scan + block sum ----
__global__ __launch_bounds__(1024) void k_scan1(const unsigned long long* __restrict__ pk,
                                                int* __restrict__ cnt,
                                                float* __restrict__ dinv,
                                                int* __restrict__ cursor,
                                                int* __restrict__ bsum, int N) {
  __shared__ int buf[1024];
  const int t = threadIdx.x;
  const int i = blockIdx.x * 1024 + t;
  int v = 0;
  if (i < N) {
    unsigned long long p = pk[i];
    v = (int)(p >> 40);
    cnt[i] = v;
    dinv[i] = rsqrtf(1.0f + (float)(p & MASK40) * (1.0f / Q24));
  }
  buf[t] = v;
  __syncthreads();
  for (int off = 1; off < 1024; off <<= 1) {
    int add = (t >= off) ? buf[t - off] : 0;
    __syncthreads();
    buf[t] += add;
    __syncthreads();
  }
  if (i < N) cursor[i] = buf[t] - v;       // exclusive, block-local
  if (t == 1023) bsum[blockIdx.x] = buf[t];
}

// ---- scan phase 2: tiny exclusive prefix of block sums ---------------------
__global__ void k_scan2(const int* __restrict__ bsum, int* __restrict__ bpre, int B) {
  if (threadIdx.x == 0) {
    int run = 0;
    for (int b = 0; b < B; ++b) { bpre[b] = run; run += bsum[b]; }
  }
}

// ------- fill CSR, atomic-free: pos = cursor_local[d] + bpre[d>>10] + rank --
__global__ __launch_bounds__(256) void k_fill(const int* __restrict__ src,
                                              const int* __restrict__ dst,
                                              const float* __restrict__ w,
                                              const int* __restrict__ rank,
                                              const float* __restrict__ dinv,
                                              const int* __restrict__ cursor,
                                              const int* __restrict__ bpre,
                                              int2* __restrict__ sorted, int E) {
  int e = blockIdx.x * 256 + threadIdx.x;
  if (e < E) {
    int d = dst[e];
    int s = src[e];
    float sw = dinv[s] * w[e];
    int pos = cursor[d] + bpre[d >> 10] + rank[e];
    sorted[pos] = make_int2(s, __float_as_int(sw));
  }
}

// ---- gather-aggregate + fused relu·dot: 8 lanes/node (uint4), 8 nodes/wave -
// ---- + last-block epilogue: sigmoid(gacc + fc_b) -> out --------------------
__global__ __launch_bounds__(256) void k_agg(const int2* __restrict__ sorted,
                                             const int* __restrict__ cursor,
                                             const int* __restrict__ bpre,
                                             const int* __restrict__ cnt,
                                             const float* __restrict__ dinv,
                                             const unsigned short* __restrict__ hb,
                                             const float* __restrict__ b,
                                             const float* __restrict__ fcw,
                                             float* __restrict__ gacc,
                                             unsigned int* __restrict__ done,
                                             const float* __restrict__ fcb,
                                             float* __restrict__ out,
                                             int N, int nBlocks) {
  const int wid = threadIdx.x >> 6;
  const int lane = threadIdx.x & 63;
  const int seg = lane >> 3;        // 0..7: node segment within wave
  const int sl = lane & 7;          // lane within segment: 8 x uint4 = 64 f
  const int n = blockIdx.x * 32 + wid * 8 + seg;
  const uint4* h4 = (const uint4*)hb;      // 8 uint4 per row
  float p = 0.0f;
  if (n < N) {
    float dn = dinv[n];
    float dn2 = dn * dn;
    uint4 rn = h4[(size_t)n * 8 + sl];
    float4 b0 = ((const float4*)b)[sl * 2];
    float4 b1 = ((const float4*)b)[sl * 2 + 1];
    float a0 = b0.x + dn2 * blo(rn.x), a1 = b0.y + dn2 * bhi(rn.x);
    float a2 = b0.z + dn2 * blo(rn.y), a3 = b0.w + dn2 * bhi(rn.y);
    float a4 = b1.x + dn2 * blo(rn.z), a5 = b1.y + dn2 * bhi(rn.z);
    float a6 = b1.z + dn2 * blo(rn.w), a7 = b1.w + dn2 * bhi(rn.w);
    int e = cursor[n] + bpre[n >> 10];
    int end = e + cnt[n];
    for (; e + 1 < end; e += 2) {
      int2 e0 = sorted[e];
      int2 e1 = sorted[e + 1];
      uint4 r0 = h4[(size_t)e0.x * 8 + sl];
      uint4 r1 = h4[(size_t)e1.x * 8 + sl];
      float n0 = dn * __int_as_float(e0.y);
      float n1 = dn * __int_as_float(e1.y);
      a0 += n0 * blo(r0.x) + n1 * blo(r1.x);
      a1 += n0 * bhi(r0.x) + n1 * bhi(r1.x);
      a2 += n0 * blo(r0.y) + n1 * blo(r1.y);
      a3 += n0 * bhi(r0.y) + n1 * bhi(r1.y);
      a4 += n0 * blo(r0.z) + n1 * blo(r1.z);
      a5 += n0 * bhi(r0.z) + n1 * bhi(r1.z);
      a6 += n0 * blo(r0.w) + n1 * blo(r1.w);
      a7 += n0 * bhi(r0.w) + n1 * bhi(r1.w);
    }
    if (e < end) {
      int2 e0 = sorted[e];
      uint4 r0 = h4[(size_t)e0.x * 8 + sl];
      float n0 = dn * __int_as_float(e0.y);
      a0 += n0 * blo(r0.x); a1 += n0 * bhi(r0.x);
      a2 += n0 * blo(r0.y); a3 += n0 * bhi(r0.y);
      a4 += n0 * blo(r0.z); a5 += n0 * bhi(r0.z);
      a6 += n0 * blo(r0.w); a7 += n0 * bhi(r0.w);
    }
    float4 f0 = ((const float4*)fcw)[(size_t)n * 16 + sl * 2];
    float4 f1 = ((const float4*)fcw)[(size_t)n * 16 + sl * 2 + 1];
    p = fmaxf(a0, 0.f) * f0.x + fmaxf(a1, 0.f) * f0.y +
        fmaxf(a2, 0.f) * f0.z + fmaxf(a3, 0.f) * f0.w +
        fmaxf(a4, 0.f) * f1.x + fmaxf(a5, 0.f) * f1.y +
        fmaxf(a6, 0.f) * f1.z + fmaxf(a7, 0.f) * f1.w;
  }
  p += __shfl_down(p, 4);
  p += __shfl_down(p, 2);
  p += __shfl_down(p, 1);
  __shared__ float ls[32];
  if (sl == 0) ls[wid * 8 + seg] = p;
  __syncthreads();
  if (threadIdx.x == 0) {
    float s = 0.f;
#pragma unroll
    for (int i = 0; i < 32; ++i) s += ls[i];
    atomicAdd(gacc, s);
    __threadfence();
    unsigned int ticket = atomicAdd(done, 1u);
    if (ticket == (unsigned int)(nBlocks - 1)) {
      float tot = atomicAdd(gacc, 0.0f);   // coherent read of final sum
      float logit = tot + fcb[0];
      out[0] = 1.0f / (1.0f + expf(-logit));
    }
  }
}

extern "C" void kernel_launch(void* const* d_in, const int* in_sizes, int n_in,
                              void* d_out, int out_size, void* d_ws, size_t ws_size,
                              hipStream_t stream) {
  const float* x      = (const float*)d_in[0];
  const int*   elist  = (const int*)d_in[1];
  const float* eattr  = (const float*)d_in[2];
  const float* conv_w = (const float*)d_in[3];
  const float* conv_b = (const float*)d_in[4];
  const float* fc_w   = (const float*)d_in[5];
  const float* fc_b   = (const float*)d_in[6];
  float* out = (float*)d_out;

  const int N = in_sizes[0] / F;   // 50000
  const int E = in_sizes[2];       // 1,600,000
  const int* src = elist;
  const int* dst = elist + E;

  char* wsb = (char*)d_ws;
  int2*  sorted = (int2*)wsb;                                   // E*8 B
  unsigned long long* pk = (unsigned long long*)(wsb + (size_t)E * 8);  // N*8 B
  int*   rank   = (int*)(pk + N);                               // E*4 B
  unsigned short* hb = (unsigned short*)(rank + E);             // N*H*2 B
  int*   cnt    = (int*)(hb + (size_t)N * H);                   // N*4
  int*   cursor = cnt + N;                                      // N*4
  float* dinv   = (float*)(cursor + N);                         // N*4
  const int nScan = (N + 1023) / 1024;
  int*   bsum   = (int*)(dinv + N);                             // nScan*4
  int*   bpre   = bsum + nScan;                                 // nScan*4
  float* gacc   = (float*)(bpre + nScan);                       // 1
  unsigned int* done = (unsigned int*)(gacc + 1);               // 1

  const int G = (N + NB - 1) / NB;         // gemm blocks
  const int C = (E + 255) / 256;           // count blocks
  const int nAgg = (N + 31) / 32;

  k_init<<<(N + 255) / 256, 256, 0, stream>>>(pk, gacc, done, N);
  k_mix<<<G + C, 256, 0, stream>>>(x, conv_w, hb, N, dst, eattr, pk, rank, E, G);
  k_scan1<<<nScan, 1024, 0, stream>>>(pk, cnt, dinv, cursor, bsum, N);
  k_scan2<<<1, 64, 0, stream>>>(bsum, bpre, nScan);
  k_fill<<<(E + 255) / 256, 256, 0, stream>>>(src, dst, eattr, rank, dinv, cursor,
                                              bpre, sorted, E);
  k_agg<<<nAgg, 256, 0, stream>>>(sorted, cursor, bpre, cnt, dinv, hb, conv_b, fc_w,
                                  gacc, done, fc_b, out, N, nAgg);
}